// Round 1
// 1024.139 us; speedup vs baseline: 1.2680x; 1.2680x over previous
//
#include <hip/hip_runtime.h>
#include <hip/hip_bf16.h>
#include <math.h>

#define B_ 8
#define N_ 1024
#define C_ 256
#define H_ 8
#define D_ 32
#define F_ 682
#define FP_ 704   // F padded to multiple of 32
#define EPS_ 1e-3f

typedef const __hip_bfloat16* bf16cp;
typedef __hip_bfloat16 bf16;
typedef __attribute__((ext_vector_type(8))) short short8;
typedef __attribute__((ext_vector_type(4))) float f32x4;

__device__ __forceinline__ float b2f(bf16 v){ return __bfloat162float(v); }
__device__ __forceinline__ float us2f(unsigned int u){ return __uint_as_float(u << 16); }
__device__ __forceinline__ unsigned short f2bu(float f){   // f32 -> bf16 bits, RNE
  unsigned int u = __float_as_uint(f);
  return (unsigned short)((u + 0x7FFFu + ((u >> 16) & 1u)) >> 16);
}

// flag-aware load: bf=1 -> bf16, bf=0 -> f32
__device__ __forceinline__ float ldf(const void* p, size_t i, int bf){
  return bf ? b2f(((bf16cp)p)[i]) : ((const float*)p)[i];
}

struct Ptrs { const void* p[22]; };

// ---------------- per-tensor dtype sniffer ----------------
__global__ void k_sniff(Ptrs ptrs, int* flags){
  if (threadIdx.x != 0 || blockIdx.x != 0) return;
  const int sizes[22] = {2097152, 8388608, 8388608, 196608, 768, 64, 8, 64, 8,
                         65536, 256, 256, 256, 256, 256, 256, 256,
                         174592, 174592, 174592, 682, 682};
  for (int i = 0; i < 22; i++){
    if (i == 1){ flags[i] = 0; continue; }
    const unsigned short* u = (const unsigned short*)ptrs.p[i];
    int nu = sizes[i] < 64 ? sizes[i] : 64;
    int badB = 0, badF = 0, evenAllZero = 1, oddAny = 0;
    for (int j = 0; j < nu; j++){
      unsigned short x = u[j];
      float vb = us2f((unsigned int)x);
      float ab = fabsf(vb);
      if (!(vb == 0.0f) && (!(ab <= 1e3f) || ab < 1e-30f || vb != vb)) badB++;
      if ((j & 1) == 0){ if (x) evenAllZero = 0; }
      else            { if (x) oddAny = 1; }
    }
    for (int j = 0; j + 1 < nu; j += 2){
      unsigned int w = ((unsigned int)u[j]) | (((unsigned int)u[j+1]) << 16);
      float vf = __uint_as_float(w);
      float af = fabsf(vf);
      if (!(vf == 0.0f) && (!(af <= 1e3f) || af < 1e-30f || vf != vf)) badF++;
    }
    int bf;
    if (badB > badF) bf = 0;
    else if (badF > badB) bf = 1;
    else bf = (evenAllZero && oddAny) ? 0 : 1;
    flags[i] = bf;
  }
}

// ---------------- lengths from mask diagonal ----------------
__global__ __launch_bounds__(256) void k_lengths(const unsigned char* mask, int* lengths){
  __shared__ int red[256];
  int b = blockIdx.x, t = threadIdx.x;
  unsigned char c0 = mask[0], c1 = mask[1];
  int mode;
  if (c0 == 0x80u) mode = 2;
  else if (c0 == 0u) mode = 3;
  else mode = (c1 != 0u) ? 0 : 1;
  int cnt = 0;
  for (int n = t; n < N_; n += 256){
    size_t idx = ((size_t)b*N_ + n)*N_ + n;
    int v;
    if (mode == 0)      v = (mask[idx] != 0);
    else if (mode == 1) v = (((const int*)mask)[idx] != 0);
    else if (mode == 2) v = (((const unsigned short*)mask)[idx] != 0);
    else                v = (((const float*)mask)[idx] != 0.0f);
    cnt += v;
  }
  red[t] = cnt; __syncthreads();
  for (int s = 128; s > 0; s >>= 1){ if (t < s) red[t] += red[t+s]; __syncthreads(); }
  if (t == 0) lengths[b] = red[0];
}

// ---------------- generic LayerNorm (now with row stride) ----------------
__global__ __launch_bounds__(256) void k_ln(const void* in, const int* flags, int in_mode,
                                            const void* g, int gi, const void* bia, int bi,
                                            void* out, int out_bf16, int Clen, int stride){
  __shared__ float red[256];
  int fin = (in_mode >= 0) ? flags[in_mode] : (in_mode == -2 ? 1 : 0);
  int fg = flags[gi], fb = flags[bi];
  int row = blockIdx.x, t = threadIdx.x;
  size_t base = (size_t)row * stride;
  float xs[3];
  int nv = (Clen + 255) >> 8;
  float s = 0.f;
  for (int i = 0; i < nv; i++){
    int c = t + (i << 8);
    float v = 0.f;
    if (c < Clen) v = ldf(in, base+c, fin);
    xs[i] = v; s += v;
  }
  red[t] = s; __syncthreads();
  for (int st = 128; st > 0; st >>= 1){ if (t < st) red[t] += red[t+st]; __syncthreads(); }
  float mean = red[0] / (float)Clen; __syncthreads();
  float s2 = 0.f;
  for (int i = 0; i < nv; i++){
    int c = t + (i << 8);
    if (c < Clen){ float d = xs[i] - mean; s2 += d*d; }
  }
  red[t] = s2; __syncthreads();
  for (int st = 128; st > 0; st >>= 1){ if (t < st) red[t] += red[t+st]; __syncthreads(); }
  float rstd = rsqrtf(red[0] / (float)Clen + EPS_);
  for (int i = 0; i < nv; i++){
    int c = t + (i << 8);
    if (c < Clen){
      float v = (xs[i]-mean)*rstd*ldf(g,c,fg) + ldf(bia,c,fb);
      if (out_bf16) ((bf16*)out)[base+c] = __float2bfloat16(v);
      else          ((float*)out)[base+c] = v;
    }
  }
}

// ---------------- weight prep: transpose + convert to bf16 [N][K], zero-padded ----------------
// dst[n*Kp + k] = src[k*Nsrc + n], 0 where out of src range.
__global__ __launch_bounds__(256) void k_prepw(Ptrs ptrs, const int* flags,
                                               unsigned short* wqkvT, unsigned short* woutT,
                                               unsigned short* wwideT, unsigned short* wgateT,
                                               unsigned short* wdownT){
  __shared__ unsigned short tile[32][33];
  int which = blockIdx.y;
  const void* src; unsigned short* dst; int f, Ksrc, Nsrc, Np, Kp;
  switch (which){
    case 0:  src = ptrs.p[3];  f = flags[3];  Ksrc = 256; Nsrc = 768; Np = 768; Kp = 256; dst = wqkvT; break;
    case 1:  src = ptrs.p[9];  f = flags[9];  Ksrc = 256; Nsrc = 256; Np = 256; Kp = 256; dst = woutT; break;
    case 2:  src = ptrs.p[17]; f = flags[17]; Ksrc = 256; Nsrc = F_;  Np = FP_; Kp = 256; dst = wwideT; break;
    case 3:  src = ptrs.p[18]; f = flags[18]; Ksrc = 256; Nsrc = F_;  Np = FP_; Kp = 256; dst = wgateT; break;
    default: src = ptrs.p[19]; f = flags[19]; Ksrc = F_;  Nsrc = 256; Np = 256; Kp = FP_; dst = wdownT; break;
  }
  int tilesN = (Np + 31) >> 5, tilesK = (Kp + 31) >> 5;
  int tid = blockIdx.x;
  if (tid >= tilesN * tilesK) return;
  int tn = tid % tilesN, tk = tid / tilesN;
  int n0 = tn << 5, k0 = tk << 5;
  int tx = threadIdx.x & 31, ty = threadIdx.x >> 5;
  #pragma unroll
  for (int i = 0; i < 4; i++){
    int k = k0 + ty + i*8, n = n0 + tx;
    float v = (k < Ksrc && n < Nsrc) ? ldf(src, (size_t)k*Nsrc + n, f) : 0.f;
    tile[ty + i*8][tx] = f2bu(v);
  }
  __syncthreads();
  #pragma unroll
  for (int i = 0; i < 4; i++){
    int n = n0 + ty + i*8, k = k0 + tx;
    if (n < Np && k < Kp) dst[(size_t)n*Kp + k] = tile[tx][ty + i*8];
  }
}

// ---------------- MFMA GEMM core: 128x128 tile, BK=32, 4 waves (2x2), 4x4 frags/wave ----------------
// A [M][K] bf16 row-major, BT [N][K] bf16 row-major (i.e. B transposed). K % 32 == 0.
// LDS tiles padded: row stride 40 ushorts (80 B) -> only 2-way bank aliasing (free).
__device__ __forceinline__ void gemm128_core(const unsigned short* A, const unsigned short* BT,
                                             int K, int m0, int n0,
                                             unsigned short* As, unsigned short* Bs,
                                             f32x4 (&acc)[4][4]){
  int t = threadIdx.x;
  int lane = t & 63, w = t >> 6, wr = w >> 1, wc = w & 1;
  int cl = lane & 15, cq = lane >> 4;
  int r0 = t >> 2, o0 = (t & 3) << 3;
  const unsigned short* Ap = A + (size_t)(m0 + r0) * K + o0;
  const unsigned short* Bp = BT + (size_t)(n0 + r0) * K + o0;
  for (int k0 = 0; k0 < K; k0 += 32){
    short8 a0 = *(const short8*)(Ap + k0);
    short8 a1 = *(const short8*)(Ap + (size_t)64*K + k0);
    short8 b0 = *(const short8*)(Bp + k0);
    short8 b1 = *(const short8*)(Bp + (size_t)64*K + k0);
    __syncthreads();
    *(short8*)(As + r0*40 + o0)      = a0;
    *(short8*)(As + (r0+64)*40 + o0) = a1;
    *(short8*)(Bs + r0*40 + o0)      = b0;
    *(short8*)(Bs + (r0+64)*40 + o0) = b1;
    __syncthreads();
    short8 af[4], bfr[4];
    #pragma unroll
    for (int i = 0; i < 4; i++){
      af[i]  = *(const short8*)(As + (wr*64 + i*16 + cl)*40 + cq*8);
      bfr[i] = *(const short8*)(Bs + (wc*64 + i*16 + cl)*40 + cq*8);
    }
    #pragma unroll
    for (int i = 0; i < 4; i++)
      #pragma unroll
      for (int j = 0; j < 4; j++)
        acc[i][j] = __builtin_amdgcn_mfma_f32_16x16x32_bf16(af[i], bfr[j], acc[i][j], 0, 0, 0);
  }
}

// ---------------- QKV projection: [8192,256] x [256,768] ----------------
__global__ __launch_bounds__(256) void k_qkv(const bf16* Abuf, const unsigned short* WT,
                                             const void* bias, const int* flags,
                                             bf16* qb, bf16* kb, bf16* vb){
  __shared__ unsigned short As[128*40], Bs[128*40];
  int fb = flags[4];
  int m0 = blockIdx.x * 128, n0 = blockIdx.y * 128;
  f32x4 acc[4][4];
  #pragma unroll
  for (int i = 0; i < 4; i++)
    #pragma unroll
    for (int j = 0; j < 4; j++){ f32x4 z = {0.f,0.f,0.f,0.f}; acc[i][j] = z; }
  gemm128_core((const unsigned short*)Abuf, WT, C_, m0, n0, As, Bs, acc);
  int t = threadIdx.x, lane = t & 63, w = t >> 6, wr = w >> 1, wc = w & 1;
  int cl = lane & 15, cq = lane >> 4;
  #pragma unroll
  for (int j = 0; j < 4; j++){
    int n = n0 + wc*64 + j*16 + cl;
    float bv = ldf(bias, n, fb);
    int three = n >> 8, hh = (n >> 5) & 7, d = n & 31;
    bf16* dst = (three == 0) ? qb : ((three == 1) ? kb : vb);
    #pragma unroll
    for (int i = 0; i < 4; i++){
      #pragma unroll
      for (int r = 0; r < 4; r++){
        int m = m0 + wr*64 + i*16 + cq*4 + r;
        int bb = m >> 10, nn = m & 1023;
        dst[(((size_t)bb*H_ + hh)*N_ + nn)*D_ + d] = __float2bfloat16(acc[i][j][r] + bv);
      }
    }
  }
}

// ---------------- out projection + LayerScale residual ----------------
__global__ __launch_bounds__(256) void k_outproj(const bf16* Abuf, const unsigned short* WT,
                                                 const void* bias, const void* inputs,
                                                 const void* gamma1, const int* flags, float* xout){
  __shared__ unsigned short As[128*40], Bs[128*40];
  int fb = flags[10], fin = flags[0], fg = flags[15];
  int m0 = blockIdx.x * 128, n0 = blockIdx.y * 128;
  f32x4 acc[4][4];
  #pragma unroll
  for (int i = 0; i < 4; i++)
    #pragma unroll
    for (int j = 0; j < 4; j++){ f32x4 z = {0.f,0.f,0.f,0.f}; acc[i][j] = z; }
  gemm128_core((const unsigned short*)Abuf, WT, C_, m0, n0, As, Bs, acc);
  int t = threadIdx.x, lane = t & 63, w = t >> 6, wr = w >> 1, wc = w & 1;
  int cl = lane & 15, cq = lane >> 4;
  #pragma unroll
  for (int j = 0; j < 4; j++){
    int n = n0 + wc*64 + j*16 + cl;
    float bv = ldf(bias, n, fb);
    float gv = ldf(gamma1, n, fg);
    #pragma unroll
    for (int i = 0; i < 4; i++){
      #pragma unroll
      for (int r = 0; r < 4; r++){
        int m = m0 + wr*64 + i*16 + cq*4 + r;
        size_t idx = (size_t)m*C_ + n;
        xout[idx] = ldf(inputs, idx, fin) + gv * (acc[i][j][r] + bv);
      }
    }
  }
}

__device__ __forceinline__ float gelu_exact(float x){
  return 0.5f * x * (1.0f + erff(x * 0.70710678118654752f));
}

// ---------------- FFN up: dual GEMM [8192,256] x [256,682] (wide & gate), fused GLU ----------------
// 128x64 tile, 4 waves (2x2), wave tile 64x32 per output.
__global__ __launch_bounds__(256) void k_ffn1(const bf16* Abuf, const unsigned short* WwT,
                                              const unsigned short* WgT, bf16* fout){
  __shared__ unsigned short As[128*40], Bw[64*40], Bg[64*40];
  int m0 = blockIdx.x * 128, n0 = blockIdx.y * 64;
  int t = threadIdx.x, lane = t & 63, w = t >> 6, wr = w >> 1, wc = w & 1;
  int cl = lane & 15, cq = lane >> 4;
  int r0 = t >> 2, o0 = (t & 3) << 3;
  const unsigned short* A = (const unsigned short*)Abuf;
  f32x4 acc1[4][2], acc2[4][2];
  #pragma unroll
  for (int i = 0; i < 4; i++)
    #pragma unroll
    for (int j = 0; j < 2; j++){ f32x4 z = {0.f,0.f,0.f,0.f}; acc1[i][j] = z; acc2[i][j] = z; }
  const unsigned short* Ap = A + (size_t)(m0 + r0) * C_ + o0;
  const unsigned short* Bwp = WwT + (size_t)(n0 + r0) * C_ + o0;
  const unsigned short* Bgp = WgT + (size_t)(n0 + r0) * C_ + o0;
  for (int k0 = 0; k0 < C_; k0 += 32){
    short8 a0 = *(const short8*)(Ap + k0);
    short8 a1 = *(const short8*)(Ap + (size_t)64*C_ + k0);
    short8 b0, c0;
    if (r0 < 64){
      b0 = *(const short8*)(Bwp + k0);
      c0 = *(const short8*)(Bgp + k0);
    }
    __syncthreads();
    *(short8*)(As + r0*40 + o0)      = a0;
    *(short8*)(As + (r0+64)*40 + o0) = a1;
    if (r0 < 64){
      *(short8*)(Bw + r0*40 + o0) = b0;
      *(short8*)(Bg + r0*40 + o0) = c0;
    }
    __syncthreads();
    short8 af[4], bfr[2], cfr[2];
    #pragma unroll
    for (int i = 0; i < 4; i++)
      af[i] = *(const short8*)(As + (wr*64 + i*16 + cl)*40 + cq*8);
    #pragma unroll
    for (int j = 0; j < 2; j++){
      bfr[j] = *(const short8*)(Bw + (wc*32 + j*16 + cl)*40 + cq*8);
      cfr[j] = *(const short8*)(Bg + (wc*32 + j*16 + cl)*40 + cq*8);
    }
    #pragma unroll
    for (int i = 0; i < 4; i++)
      #pragma unroll
      for (int j = 0; j < 2; j++){
        acc1[i][j] = __builtin_amdgcn_mfma_f32_16x16x32_bf16(af[i], bfr[j], acc1[i][j], 0, 0, 0);
        acc2[i][j] = __builtin_amdgcn_mfma_f32_16x16x32_bf16(af[i], cfr[j], acc2[i][j], 0, 0, 0);
      }
  }
  #pragma unroll
  for (int j = 0; j < 2; j++){
    int n = n0 + wc*32 + j*16 + cl;
    #pragma unroll
    for (int i = 0; i < 4; i++){
      #pragma unroll
      for (int r = 0; r < 4; r++){
        int m = m0 + wr*64 + i*16 + cq*4 + r;
        float v = (n < F_) ? gelu_exact(acc1[i][j][r]) * acc2[i][j][r] : 0.f;
        fout[(size_t)m*FP_ + n] = __float2bfloat16(v);
      }
    }
  }
}

// ---------------- FFN down + LayerScale residual: [8192,704] x [704,256] (zero-padded K) ----------------
__global__ __launch_bounds__(256) void k_down(const bf16* Abuf, const unsigned short* WT,
                                              const float* xbuf, const void* gamma2,
                                              const int* flags, void* out){
  __shared__ unsigned short As[128*40], Bs[128*40];
  int fg = flags[16], fo = flags[0];
  int m0 = blockIdx.x * 128, n0 = blockIdx.y * 128;
  f32x4 acc[4][4];
  #pragma unroll
  for (int i = 0; i < 4; i++)
    #pragma unroll
    for (int j = 0; j < 4; j++){ f32x4 z = {0.f,0.f,0.f,0.f}; acc[i][j] = z; }
  gemm128_core((const unsigned short*)Abuf, WT, FP_, m0, n0, As, Bs, acc);
  int t = threadIdx.x, lane = t & 63, w = t >> 6, wr = w >> 1, wc = w & 1;
  int cl = lane & 15, cq = lane >> 4;
  #pragma unroll
  for (int j = 0; j < 4; j++){
    int n = n0 + wc*64 + j*16 + cl;
    float gv = ldf(gamma2, n, fg);
    #pragma unroll
    for (int i = 0; i < 4; i++){
      #pragma unroll
      for (int r = 0; r < 4; r++){
        int m = m0 + wr*64 + i*16 + cq*4 + r;
        size_t idx = (size_t)m*C_ + n;
        float val = xbuf[idx] + gv * acc[i][j][r];
        if (fo) ((bf16*)out)[idx] = __float2bfloat16(val);
        else    ((float*)out)[idx] = val;
      }
    }
  }
}

// ---------------- Vsum[b][g][d] = sum_m V ----------------
__global__ __launch_bounds__(256) void k_vsum(const bf16* vb, float* vsum){
  __shared__ float red[8][32];
  int bg = blockIdx.x;            // b*8+g
  int t = threadIdx.x;
  int d = t & 31, mg = t >> 5;
  float s = 0.f;
  for (int m = mg*128; m < mg*128 + 128; m++)
    s += b2f(vb[((size_t)bg*N_ + m)*D_ + d]);
  red[mg][d] = s; __syncthreads();
  if (t < 32){
    float a = 0.f;
    #pragma unroll
    for (int i = 0; i < 8; i++) a += red[i][t];
    vsum[(size_t)bg*D_ + t] = a;
  }
}

// ============ MFMA attention pass A: softmax stats (M, L) per (b,g,n) ============
__global__ __launch_bounds__(256) void k_stats2(const bf16* qb, const bf16* kb,
                                                const void* Wt1, const void* bt1, const void* inter,
                                                const int* flags, const int* lengths, float2* stats){
  __shared__ float w1s[64], b1v[8];
  __shared__ float swM[4][8][16], swL[4][8][16];
  int fw1 = flags[5], fb1 = flags[6], fint = flags[2];
  int t = threadIdx.x;
  int ntile = blockIdx.x, b = blockIdx.y;
  int n0 = ntile * 16;
  int len = lengths[b];
  if (t < 64) w1s[t] = ldf(Wt1, t, fw1) * 0.17677669529663687f;  // fold 1/sqrt(32)
  if (t < 8)  b1v[t] = ldf(bt1, t, fb1);
  __syncthreads();
  int lane = t & 63, w = t >> 6;
  int c = lane & 15, q = lane >> 4;
  const unsigned short* qus = (const unsigned short*)qb;
  const unsigned short* kus = (const unsigned short*)kb;
  short8 qfrag[8];
  #pragma unroll
  for (int h = 0; h < 8; h++)
    qfrag[h] = *(const short8*)(qus + (((size_t)b*8 + h)*N_ + n0 + c)*D_ + q*8);
  int n_g = n0 + c;
  float M[8], L[8];
  #pragma unroll
  for (int g = 0; g < 8; g++){ M[g] = -1e30f; L[g] = 0.f; }

  for (int ci = 0; ci < 8; ci++){
    int m0c = w*256 + ci*32;
    #pragma unroll
    for (int mt = 0; mt < 2; mt++){
      int m0t = m0c + mt*16;
      f32x4 sfr[8];
      #pragma unroll
      for (int h = 0; h < 8; h++){
        short8 kf = *(const short8*)(kus + (((size_t)b*8 + h)*N_ + m0t + c)*D_ + q*8);
        f32x4 z = {0.f,0.f,0.f,0.f};
        sfr[h] = __builtin_amdgcn_mfma_f32_16x16x32_bf16(kf, qfrag[h], z, 0, 0, 0);
      }
      float ifl[4][8];
      #pragma unroll
      for (int r = 0; r < 4; r++){
        int m = m0t + q*4 + r;
        size_t i8 = ((size_t)b*N_ + n_g)*N_ + m;
        if (fint){
          uint4 iv = *(const uint4*)((const unsigned short*)inter + i8*8);
          ifl[r][0]=us2f(iv.x&0xffffu); ifl[r][1]=us2f(iv.x>>16);
          ifl[r][2]=us2f(iv.y&0xffffu); ifl[r][3]=us2f(iv.y>>16);
          ifl[r][4]=us2f(iv.z&0xffffu); ifl[r][5]=us2f(iv.z>>16);
          ifl[r][6]=us2f(iv.w&0xffffu); ifl[r][7]=us2f(iv.w>>16);
        } else {
          const float* fp = (const float*)inter + i8*8;
          #pragma unroll
          for (int g = 0; g < 8; g++) ifl[r][g] = fp[g];
        }
      }
      #pragma unroll
      for (int g = 0; g < 8; g++){
        float sv[4];
        #pragma unroll
        for (int r = 0; r < 4; r++){
          int m = m0t + q*4 + r;
          float v = b1v[g] + ifl[r][g];
          #pragma unroll
          for (int h = 0; h < 8; h++) v += sfr[h][r] * w1s[h*8 + g];
          bool ok = (n_g >= len) || (m < len);
          sv[r] = ok ? v : -1e30f;
        }
        float tmax = fmaxf(fmaxf(sv[0], sv[1]), fmaxf(sv[2], sv[3]));
        float Mn = fmaxf(M[g], tmax);
        float f = __expf(M[g] - Mn);
        L[g] = L[g]*f + __expf(sv[0]-Mn) + __expf(sv[1]-Mn) + __expf(sv[2]-Mn) + __expf(sv[3]-Mn);
        M[g] = Mn;
      }
    }
  }
  #pragma unroll
  for (int g = 0; g < 8; g++){
    #pragma unroll
    for (int sft = 16; sft <= 32; sft <<= 1){
      float Mo = __shfl_xor(M[g], sft);
      float Lo = __shfl_xor(L[g], sft);
      float Mn = fmaxf(M[g], Mo);
      L[g] = L[g]*__expf(M[g]-Mn) + Lo*__expf(Mo-Mn);
      M[g] = Mn;
    }
  }
  if (lane < 16){
    #pragma unroll
    for (int g = 0; g < 8; g++){ swM[w][g][c] = M[g]; swL[w][g][c] = L[g]; }
  }
  __syncthreads();
  if (t < 128){
    int g = t >> 4, nl = t & 15;
    float Mf = fmaxf(fmaxf(swM[0][g][nl], swM[1][g][nl]), fmaxf(swM[2][g][nl], swM[3][g][nl]));
    float Lf = 0.f;
    #pragma unroll
    for (int wv = 0; wv < 4; wv++) Lf += swL[wv][g][nl] * __expf(swM[wv][g][nl] - Mf);
    stats[((size_t)b*8 + g)*N_ + n0 + nl] = make_float2(Mf, Lf);
  }
}

// ============ MFMA attention pass B: scores -> p -> th2 mix -> PV ============
__global__ __launch_bounds__(256) void k_attn2(const bf16* qb, const bf16* kb, const bf16* vb,
                                               const void* Wt1, const void* bt1,
                                               const void* Wt2, const void* bt2,
                                               const void* inter, const int* flags,
                                               const int* lengths, const float2* stats,
                                               const float* vsum, bf16* aobuf){
  __shared__ unsigned short a2s[4][8][640];   // [wave][head][n*40 + m], stride 40 hw
  __shared__ unsigned short vts[4][1280];     // [wave][d*40 + m]
  __shared__ float w1s[64], w2s[64], b1v[8], b2v[8];
  __shared__ float moff[8][16];
  __shared__ float vsumS[8][32];
  __shared__ float osum[4][528];              // [wave][n*33 + d]
  int fw1 = flags[5], fb1 = flags[6], fw2 = flags[7], fb2 = flags[8], fint = flags[2];
  int t = threadIdx.x;
  int ntile = blockIdx.x, b = blockIdx.y;
  int n0 = ntile * 16;
  int len = lengths[b];
  if (t < 64){ w1s[t] = ldf(Wt1, t, fw1) * 0.17677669529663687f; w2s[t] = ldf(Wt2, t, fw2); }
  if (t < 8){ b1v[t] = ldf(bt1, t, fb1); b2v[t] = ldf(bt2, t, fb2); }
  if (t < 128){
    int g = t >> 4, nl = t & 15;
    float2 st = stats[((size_t)b*8 + g)*N_ + n0 + nl];
    moff[g][nl] = st.x + __logf(st.y);       // p = exp(s - moff)
  }
  {
    int g = t >> 5, d = t & 31;
    vsumS[g][d] = vsum[((size_t)b*8 + g)*D_ + d];
  }
  __syncthreads();
  int lane = t & 63, w = t >> 6;
  int c = lane & 15, q = lane >> 4;
  const unsigned short* qus = (const unsigned short*)qb;
  const unsigned short* kus = (const unsigned short*)kb;
  const unsigned short* vus = (const unsigned short*)vb;
  short8 qfrag[8];
  #pragma unroll
  for (int h = 0; h < 8; h++)
    qfrag[h] = *(const short8*)(qus + (((size_t)b*8 + h)*N_ + n0 + c)*D_ + q*8);
  float moffreg[8][4];
  #pragma unroll
  for (int g = 0; g < 8; g++)
    #pragma unroll
    for (int r = 0; r < 4; r++) moffreg[g][r] = moff[g][q*4 + r];
  f32x4 acc[8][2];
  #pragma unroll
  for (int gg = 0; gg < 8; gg++){ f32x4 z = {0.f,0.f,0.f,0.f}; acc[gg][0] = z; acc[gg][1] = z; }

  for (int ci = 0; ci < 8; ci++){
    int m0c = w*256 + ci*32;
    #pragma unroll
    for (int mt = 0; mt < 2; mt++){
      int m0t = m0c + mt*16;
      f32x4 sfr[8];
      #pragma unroll
      for (int h = 0; h < 8; h++){
        short8 kf = *(const short8*)(kus + (((size_t)b*8 + h)*N_ + m0t + c)*D_ + q*8);
        f32x4 z = {0.f,0.f,0.f,0.f};
        sfr[h] = __builtin_amdgcn_mfma_f32_16x16x32_bf16(qfrag[h], kf, z, 0, 0, 0);
      }
      int m_g = m0t + c;
      bool mok = (m_g < len);
      #pragma unroll
      for (int r = 0; r < 4; r++){
        int n_l = q*4 + r, n_gg = n0 + n_l;
        size_t i8 = ((size_t)b*N_ + n_gg)*N_ + m_g;
        float ifl[8];
        if (fint){
          uint4 iv = *(const uint4*)((const unsigned short*)inter + i8*8);
          ifl[0]=us2f(iv.x&0xffffu); ifl[1]=us2f(iv.x>>16);
          ifl[2]=us2f(iv.y&0xffffu); ifl[3]=us2f(iv.y>>16);
          ifl[4]=us2f(iv.z&0xffffu); ifl[5]=us2f(iv.z>>16);
          ifl[6]=us2f(iv.w&0xffffu); ifl[7]=us2f(iv.w>>16);
        } else {
          const float* fp = (const float*)inter + i8*8;
          #pragma unroll
          for (int g = 0; g < 8; g++) ifl[g] = fp[g];
        }
        bool ok = (n_gg >= len) || mok;
        float p[8];
        #pragma unroll
        for (int g = 0; g < 8; g++){
          float v = b1v[g] + ifl[g];
          #pragma unroll
          for (int h = 0; h < 8; h++) v += sfr[h][r] * w1s[h*8 + g];
          v = ok ? v : -1e30f;
          p[g] = __expf(v - moffreg[g][r]);
        }
        #pragma unroll
        for (int gg = 0; gg < 8; gg++){
          float a2 = 0.f;
          #pragma unroll
          for (int g = 0; g < 8; g++) a2 += p[g] * w2s[g*8 + gg];
          a2s[w][gg][n_l*40 + mt*16 + c] = f2bu(a2);
        }
      }
    }
    #pragma unroll
    for (int gg = 0; gg < 8; gg++){
      short8 v0 = *(const short8*)(vus + (((size_t)b*8 + gg)*N_ + m0c + c)*D_ + q*8);
      short8 v1 = *(const short8*)(vus + (((size_t)b*8 + gg)*N_ + m0c + 16 + c)*D_ + q*8);
      #pragma unroll
      for (int j = 0; j < 8; j++){
        vts[w][(q*8 + j)*40 + c]      = (unsigned short)v0[j];
        vts[w][(q*8 + j)*40 + 16 + c] = (unsigned short)v1[j];
      }
      short8 af  = *(const short8*)&a2s[w][gg][c*40 + q*8];
      short8 bf0 = *(const short8*)&vts[w][c*40 + q*8];
      short8 bf1 = *(const short8*)&vts[w][(16 + c)*40 + q*8];
      acc[gg][0] = __builtin_amdgcn_mfma_f32_16x16x32_bf16(af, bf0, acc[gg][0], 0, 0, 0);
      acc[gg][1] = __builtin_amdgcn_mfma_f32_16x16x32_bf16(af, bf1, acc[gg][1], 0, 0, 0);
    }
  }
  for (int gg = 0; gg < 8; gg++){
    #pragma unroll
    for (int dt = 0; dt < 2; dt++)
      #pragma unroll
      for (int r = 0; r < 4; r++)
        osum[w][(q*4 + r)*33 + dt*16 + c] = acc[gg][dt][r];
    __syncthreads();
    #pragma unroll
    for (int e = t; e < 512; e += 256){
      int nl = e >> 5, d = e & 31;
      float val = osum[0][nl*33 + d] + osum[1][nl*33 + d]
                + osum[2][nl*33 + d] + osum[3][nl*33 + d]
                + b2v[gg] * vsumS[gg][d];
      aobuf[((size_t)b*N_ + n0 + nl)*C_ + gg*D_ + d] = __float2bfloat16(val);
    }
    __syncthreads();
  }
}

// ---------------- launcher ----------------
extern "C" void kernel_launch(void* const* d_in, const int* in_sizes, int n_in,
                              void* d_out, int out_size, void* d_ws, size_t ws_size,
                              hipStream_t stream) {
  Ptrs ptrs;
  for (int i = 0; i < 22; i++) ptrs.p[i] = d_in[i];
  const unsigned char* mask = (const unsigned char*)d_in[1];

  char* ws = (char*)d_ws;
  size_t o = 0;
  size_t o_flags = o; o += 256;
  size_t o_len   = o; o += 256;
  size_t o_stats = o; o += (size_t)B_*H_*N_*sizeof(float2);   // 512 KB
  size_t o_vsum  = o; o += (size_t)B_*H_*D_*4;                // 8 KB
  size_t o_h     = o; o += (size_t)B_*N_*C_*2;                // 4 MB bf16
  size_t o_q     = o; o += (size_t)B_*N_*C_*2;
  size_t o_k     = o; o += (size_t)B_*N_*C_*2;
  size_t o_v     = o; o += (size_t)B_*N_*C_*2;
  size_t o_ao    = o; o += (size_t)B_*N_*C_*2;                // 4 MB bf16 now
  size_t o_x     = o; o += (size_t)B_*N_*C_*4;                // 8 MB f32
  size_t o_f     = o; o += (size_t)B_*N_*FP_*2;               // 11.5 MB bf16 (stride 704)
  size_t o_wq    = o; o += (size_t)768*256*2;                 // transposed weights (bf16)
  size_t o_wo    = o; o += (size_t)256*256*2;
  size_t o_ww    = o; o += (size_t)FP_*256*2;
  size_t o_wg    = o; o += (size_t)FP_*256*2;
  size_t o_wd    = o; o += (size_t)256*FP_*2;

  int*    flags   = (int*)(ws + o_flags);
  int*    lengths = (int*)(ws + o_len);
  float2* stats   = (float2*)(ws + o_stats);
  float*  vsum    = (float*)(ws + o_vsum);
  bf16*   hbuf    = (bf16*)(ws + o_h);
  bf16*   qbuf    = (bf16*)(ws + o_q);
  bf16*   kbuf    = (bf16*)(ws + o_k);
  bf16*   vbuf    = (bf16*)(ws + o_v);
  bf16*   aobuf   = (bf16*)(ws + o_ao);
  float*  xbuf    = (float*)(ws + o_x);
  bf16*   fbuf    = (bf16*)(ws + o_f);
  unsigned short* wqkvT  = (unsigned short*)(ws + o_wq);
  unsigned short* woutT  = (unsigned short*)(ws + o_wo);
  unsigned short* wwideT = (unsigned short*)(ws + o_ww);
  unsigned short* wgateT = (unsigned short*)(ws + o_wg);
  unsigned short* wdownT = (unsigned short*)(ws + o_wd);

  k_sniff<<<1, 64, 0, stream>>>(ptrs, flags);
  k_prepw<<<dim3(192, 5), 256, 0, stream>>>(ptrs, flags, wqkvT, woutT, wwideT, wgateT, wdownT);
  k_lengths<<<8, 256, 0, stream>>>(mask, lengths);
  k_ln<<<B_*N_, 256, 0, stream>>>(d_in[0], flags, 0, d_in[11], 11, d_in[12], 12, hbuf, 1, C_, C_);
  k_qkv<<<dim3(64, 6), 256, 0, stream>>>(hbuf, wqkvT, d_in[4], flags, qbuf, kbuf, vbuf);
  k_vsum<<<64, 256, 0, stream>>>(vbuf, vsum);
  k_stats2<<<dim3(64, 8), 256, 0, stream>>>(qbuf, kbuf, d_in[5], d_in[6], d_in[2],
                                            flags, lengths, stats);
  k_attn2<<<dim3(64, 8), 256, 0, stream>>>(qbuf, kbuf, vbuf, d_in[5], d_in[6], d_in[7], d_in[8],
                                           d_in[2], flags, lengths, stats, vsum, aobuf);
  k_outproj<<<dim3(64, 2), 256, 0, stream>>>(aobuf, woutT, d_in[10], d_in[0], d_in[15], flags, xbuf);
  k_ln<<<B_*N_, 256, 0, stream>>>(xbuf, flags, -1, d_in[13], 13, d_in[14], 14, hbuf, 1, C_, C_);
  k_ffn1<<<dim3(64, 11), 256, 0, stream>>>(hbuf, wwideT, wgateT, fbuf);
  k_ln<<<B_*N_, 256, 0, stream>>>(fbuf, flags, -2, d_in[20], 20, d_in[21], 21, fbuf, 1, F_, FP_);
  k_down<<<dim3(64, 2), 256, 0, stream>>>(fbuf, wdownT, xbuf, d_in[16], flags, d_out);
}

// Round 2
// 851.082 us; speedup vs baseline: 1.5258x; 1.2033x over previous
//
#include <hip/hip_runtime.h>
#include <hip/hip_bf16.h>
#include <math.h>

#define B_ 8
#define N_ 1024
#define C_ 256
#define H_ 8
#define D_ 32
#define F_ 682
#define FP_ 704   // F padded to multiple of 32
#define EPS_ 1e-3f

typedef const __hip_bfloat16* bf16cp;
typedef __hip_bfloat16 bf16;
typedef __attribute__((ext_vector_type(8))) short short8;
typedef __attribute__((ext_vector_type(4))) float f32x4;

__device__ __forceinline__ float b2f(bf16 v){ return __bfloat162float(v); }
__device__ __forceinline__ float us2f(unsigned int u){ return __uint_as_float(u << 16); }
__device__ __forceinline__ unsigned short f2bu(float f){   // f32 -> bf16 bits, RNE
  unsigned int u = __float_as_uint(f);
  return (unsigned short)((u + 0x7FFFu + ((u >> 16) & 1u)) >> 16);
}

// flag-aware load: bf=1 -> bf16, bf=0 -> f32
__device__ __forceinline__ float ldf(const void* p, size_t i, int bf){
  return bf ? b2f(((bf16cp)p)[i]) : ((const float*)p)[i];
}

struct Ptrs { const void* p[22]; };

// ---------------- per-tensor dtype sniffer (parallel: 1 block per tensor) ----------------
__global__ __launch_bounds__(64) void k_sniffp(Ptrs ptrs, int* flags){
  int i = blockIdx.x;
  int lane = threadIdx.x;
  if (i == 1){ if (lane == 0) flags[1] = 0; return; }
  const int sizes[22] = {2097152, 8388608, 8388608, 196608, 768, 64, 8, 64, 8,
                         65536, 256, 256, 256, 256, 256, 256, 256,
                         174592, 174592, 174592, 682, 682};
  const unsigned short* u = (const unsigned short*)ptrs.p[i];
  int nu = sizes[i] < 64 ? sizes[i] : 64;
  unsigned short x = 0;
  if (lane < nu) x = u[lane];
  // badB per element
  int predB = 0;
  if (lane < nu){
    float vb = us2f((unsigned int)x);
    float ab = fabsf(vb);
    predB = (!(vb == 0.0f) && (!(ab <= 1e3f) || ab < 1e-30f || vb != vb)) ? 1 : 0;
  }
  unsigned long long mB = __ballot(predB);
  int badB = __popcll(mB);
  unsigned long long mEven = __ballot(lane < nu && (lane & 1) == 0 && x != 0);
  unsigned long long mOdd  = __ballot(lane < nu && (lane & 1) == 1 && x != 0);
  int evenAllZero = (mEven == 0ull);
  int oddAny = (mOdd != 0ull);
  // badF over pairs: lane l < nu/2 handles pair (2l, 2l+1)
  unsigned short xa = (unsigned short)__shfl((int)x, (lane * 2) & 63);
  unsigned short xb = (unsigned short)__shfl((int)x, (lane * 2 + 1) & 63);
  int predF = 0;
  if (lane < (nu >> 1)){
    unsigned int w = ((unsigned int)xa) | (((unsigned int)xb) << 16);
    float vf = __uint_as_float(w);
    float af = fabsf(vf);
    predF = (!(vf == 0.0f) && (!(af <= 1e3f) || af < 1e-30f || vf != vf)) ? 1 : 0;
  }
  int badF = __popcll(__ballot(predF));
  if (lane == 0){
    int bf;
    if (badB > badF) bf = 0;
    else if (badF > badB) bf = 1;
    else bf = (evenAllZero && oddAny) ? 0 : 1;
    flags[i] = bf;
  }
}

// ---------------- lengths from mask diagonal ----------------
__global__ __launch_bounds__(256) void k_lengths(const unsigned char* mask, int* lengths){
  __shared__ int red[256];
  int b = blockIdx.x, t = threadIdx.x;
  unsigned char c0 = mask[0], c1 = mask[1];
  int mode;
  if (c0 == 0x80u) mode = 2;
  else if (c0 == 0u) mode = 3;
  else mode = (c1 != 0u) ? 0 : 1;
  int cnt = 0;
  for (int n = t; n < N_; n += 256){
    size_t idx = ((size_t)b*N_ + n)*N_ + n;
    int v;
    if (mode == 0)      v = (mask[idx] != 0);
    else if (mode == 1) v = (((const int*)mask)[idx] != 0);
    else if (mode == 2) v = (((const unsigned short*)mask)[idx] != 0);
    else                v = (((const float*)mask)[idx] != 0.0f);
    cnt += v;
  }
  red[t] = cnt; __syncthreads();
  for (int s = 128; s > 0; s >>= 1){ if (t < s) red[t] += red[t+s]; __syncthreads(); }
  if (t == 0) lengths[b] = red[0];
}

// ---------------- generic LayerNorm (row stride) ----------------
__global__ __launch_bounds__(256) void k_ln(const void* in, const int* flags, int in_mode,
                                            const void* g, int gi, const void* bia, int bi,
                                            void* out, int out_bf16, int Clen, int stride){
  __shared__ float red[256];
  int fin = (in_mode >= 0) ? flags[in_mode] : (in_mode == -2 ? 1 : 0);
  int fg = flags[gi], fb = flags[bi];
  int row = blockIdx.x, t = threadIdx.x;
  size_t base = (size_t)row * stride;
  float xs[3];
  int nv = (Clen + 255) >> 8;
  float s = 0.f;
  for (int i = 0; i < nv; i++){
    int c = t + (i << 8);
    float v = 0.f;
    if (c < Clen) v = ldf(in, base+c, fin);
    xs[i] = v; s += v;
  }
  red[t] = s; __syncthreads();
  for (int st = 128; st > 0; st >>= 1){ if (t < st) red[t] += red[t+st]; __syncthreads(); }
  float mean = red[0] / (float)Clen; __syncthreads();
  float s2 = 0.f;
  for (int i = 0; i < nv; i++){
    int c = t + (i << 8);
    if (c < Clen){ float d = xs[i] - mean; s2 += d*d; }
  }
  red[t] = s2; __syncthreads();
  for (int st = 128; st > 0; st >>= 1){ if (t < st) red[t] += red[t+st]; __syncthreads(); }
  float rstd = rsqrtf(red[0] / (float)Clen + EPS_);
  for (int i = 0; i < nv; i++){
    int c = t + (i << 8);
    if (c < Clen){
      float v = (xs[i]-mean)*rstd*ldf(g,c,fg) + ldf(bia,c,fb);
      if (out_bf16) ((bf16*)out)[base+c] = __float2bfloat16(v);
      else          ((float*)out)[base+c] = v;
    }
  }
}

// ---------------- weight prep: transpose + convert to bf16 [N][K], zero-padded ----------------
__global__ __launch_bounds__(256) void k_prepw(Ptrs ptrs, const int* flags,
                                               unsigned short* wqkvT, unsigned short* woutT,
                                               unsigned short* wwideT, unsigned short* wgateT,
                                               unsigned short* wdownT){
  __shared__ unsigned short tile[32][33];
  int which = blockIdx.y;
  const void* src; unsigned short* dst; int f, Ksrc, Nsrc, Np, Kp;
  switch (which){
    case 0:  src = ptrs.p[3];  f = flags[3];  Ksrc = 256; Nsrc = 768; Np = 768; Kp = 256; dst = wqkvT; break;
    case 1:  src = ptrs.p[9];  f = flags[9];  Ksrc = 256; Nsrc = 256; Np = 256; Kp = 256; dst = woutT; break;
    case 2:  src = ptrs.p[17]; f = flags[17]; Ksrc = 256; Nsrc = F_;  Np = FP_; Kp = 256; dst = wwideT; break;
    case 3:  src = ptrs.p[18]; f = flags[18]; Ksrc = 256; Nsrc = F_;  Np = FP_; Kp = 256; dst = wgateT; break;
    default: src = ptrs.p[19]; f = flags[19]; Ksrc = F_;  Nsrc = 256; Np = 256; Kp = FP_; dst = wdownT; break;
  }
  int tilesN = (Np + 31) >> 5, tilesK = (Kp + 31) >> 5;
  int tid = blockIdx.x;
  if (tid >= tilesN * tilesK) return;
  int tn = tid % tilesN, tk = tid / tilesN;
  int n0 = tn << 5, k0 = tk << 5;
  int tx = threadIdx.x & 31, ty = threadIdx.x >> 5;
  #pragma unroll
  for (int i = 0; i < 4; i++){
    int k = k0 + ty + i*8, n = n0 + tx;
    float v = (k < Ksrc && n < Nsrc) ? ldf(src, (size_t)k*Nsrc + n, f) : 0.f;
    tile[ty + i*8][tx] = f2bu(v);
  }
  __syncthreads();
  #pragma unroll
  for (int i = 0; i < 4; i++){
    int n = n0 + ty + i*8, k = k0 + tx;
    if (n < Np && k < Kp) dst[(size_t)n*Kp + k] = tile[tx][ty + i*8];
  }
}

// ---------------- V transpose: Vt[b][g][d][m] <- V[b][g][m][d] ----------------
__global__ __launch_bounds__(256) void k_vt(const bf16* vb, unsigned short* vt){
  __shared__ unsigned short tile[32][34];
  int mt = blockIdx.x, bg = blockIdx.y;
  int tx = threadIdx.x & 31, ty = threadIdx.x >> 5;
  const unsigned short* vus = (const unsigned short*)vb;
  #pragma unroll
  for (int i = 0; i < 4; i++){
    int m = mt*32 + ty + i*8;
    tile[ty + i*8][tx] = vus[((size_t)bg*N_ + m)*D_ + tx];
  }
  __syncthreads();
  #pragma unroll
  for (int i = 0; i < 4; i++){
    int d = ty + i*8;
    vt[((size_t)bg*D_ + d)*N_ + mt*32 + tx] = tile[tx][d];
  }
}

// ---------------- MFMA GEMM core: 128x128 tile, BK=32, 4 waves (2x2), 4x4 frags/wave ----------------
__device__ __forceinline__ void gemm128_core(const unsigned short* A, const unsigned short* BT,
                                             int K, int m0, int n0,
                                             unsigned short* As, unsigned short* Bs,
                                             f32x4 (&acc)[4][4]){
  int t = threadIdx.x;
  int lane = t & 63, w = t >> 6, wr = w >> 1, wc = w & 1;
  int cl = lane & 15, cq = lane >> 4;
  int r0 = t >> 2, o0 = (t & 3) << 3;
  const unsigned short* Ap = A + (size_t)(m0 + r0) * K + o0;
  const unsigned short* Bp = BT + (size_t)(n0 + r0) * K + o0;
  for (int k0 = 0; k0 < K; k0 += 32){
    short8 a0 = *(const short8*)(Ap + k0);
    short8 a1 = *(const short8*)(Ap + (size_t)64*K + k0);
    short8 b0 = *(const short8*)(Bp + k0);
    short8 b1 = *(const short8*)(Bp + (size_t)64*K + k0);
    __syncthreads();
    *(short8*)(As + r0*40 + o0)      = a0;
    *(short8*)(As + (r0+64)*40 + o0) = a1;
    *(short8*)(Bs + r0*40 + o0)      = b0;
    *(short8*)(Bs + (r0+64)*40 + o0) = b1;
    __syncthreads();
    short8 af[4], bfr[4];
    #pragma unroll
    for (int i = 0; i < 4; i++){
      af[i]  = *(const short8*)(As + (wr*64 + i*16 + cl)*40 + cq*8);
      bfr[i] = *(const short8*)(Bs + (wc*64 + i*16 + cl)*40 + cq*8);
    }
    #pragma unroll
    for (int i = 0; i < 4; i++)
      #pragma unroll
      for (int j = 0; j < 4; j++)
        acc[i][j] = __builtin_amdgcn_mfma_f32_16x16x32_bf16(af[i], bfr[j], acc[i][j], 0, 0, 0);
  }
}

// ---------------- QKV projection ----------------
__global__ __launch_bounds__(256) void k_qkv(const bf16* Abuf, const unsigned short* WT,
                                             const void* bias, const int* flags,
                                             bf16* qb, bf16* kb, bf16* vb){
  __shared__ unsigned short As[128*40], Bs[128*40];
  int fb = flags[4];
  int m0 = blockIdx.x * 128, n0 = blockIdx.y * 128;
  f32x4 acc[4][4];
  #pragma unroll
  for (int i = 0; i < 4; i++)
    #pragma unroll
    for (int j = 0; j < 4; j++){ f32x4 z = {0.f,0.f,0.f,0.f}; acc[i][j] = z; }
  gemm128_core((const unsigned short*)Abuf, WT, C_, m0, n0, As, Bs, acc);
  int t = threadIdx.x, lane = t & 63, w = t >> 6, wr = w >> 1, wc = w & 1;
  int cl = lane & 15, cq = lane >> 4;
  #pragma unroll
  for (int j = 0; j < 4; j++){
    int n = n0 + wc*64 + j*16 + cl;
    float bv = ldf(bias, n, fb);
    int three = n >> 8, hh = (n >> 5) & 7, d = n & 31;
    bf16* dst = (three == 0) ? qb : ((three == 1) ? kb : vb);
    #pragma unroll
    for (int i = 0; i < 4; i++){
      #pragma unroll
      for (int r = 0; r < 4; r++){
        int m = m0 + wr*64 + i*16 + cq*4 + r;
        int bb = m >> 10, nn = m & 1023;
        dst[(((size_t)bb*H_ + hh)*N_ + nn)*D_ + d] = __float2bfloat16(acc[i][j][r] + bv);
      }
    }
  }
}

// ---------------- out projection + LayerScale residual ----------------
__global__ __launch_bounds__(256) void k_outproj(const bf16* Abuf, const unsigned short* WT,
                                                 const void* bias, const void* inputs,
                                                 const void* gamma1, const int* flags, float* xout){
  __shared__ unsigned short As[128*40], Bs[128*40];
  int fb = flags[10], fin = flags[0], fg = flags[15];
  int m0 = blockIdx.x * 128, n0 = blockIdx.y * 128;
  f32x4 acc[4][4];
  #pragma unroll
  for (int i = 0; i < 4; i++)
    #pragma unroll
    for (int j = 0; j < 4; j++){ f32x4 z = {0.f,0.f,0.f,0.f}; acc[i][j] = z; }
  gemm128_core((const unsigned short*)Abuf, WT, C_, m0, n0, As, Bs, acc);
  int t = threadIdx.x, lane = t & 63, w = t >> 6, wr = w >> 1, wc = w & 1;
  int cl = lane & 15, cq = lane >> 4;
  #pragma unroll
  for (int j = 0; j < 4; j++){
    int n = n0 + wc*64 + j*16 + cl;
    float bv = ldf(bias, n, fb);
    float gv = ldf(gamma1, n, fg);
    #pragma unroll
    for (int i = 0; i < 4; i++){
      #pragma unroll
      for (int r = 0; r < 4; r++){
        int m = m0 + wr*64 + i*16 + cq*4 + r;
        size_t idx = (size_t)m*C_ + n;
        xout[idx] = ldf(inputs, idx, fin) + gv * (acc[i][j][r] + bv);
      }
    }
  }
}

__device__ __forceinline__ float gelu_exact(float x){
  return 0.5f * x * (1.0f + erff(x * 0.70710678118654752f));
}

// ---------------- FFN up: dual GEMM, fused GLU ----------------
__global__ __launch_bounds__(256) void k_ffn1(const bf16* Abuf, const unsigned short* WwT,
                                              const unsigned short* WgT, bf16* fout){
  __shared__ unsigned short As[128*40], Bw[64*40], Bg[64*40];
  int m0 = blockIdx.x * 128, n0 = blockIdx.y * 64;
  int t = threadIdx.x, lane = t & 63, w = t >> 6, wr = w >> 1, wc = w & 1;
  int cl = lane & 15, cq = lane >> 4;
  int r0 = t >> 2, o0 = (t & 3) << 3;
  const unsigned short* A = (const unsigned short*)Abuf;
  f32x4 acc1[4][2], acc2[4][2];
  #pragma unroll
  for (int i = 0; i < 4; i++)
    #pragma unroll
    for (int j = 0; j < 2; j++){ f32x4 z = {0.f,0.f,0.f,0.f}; acc1[i][j] = z; acc2[i][j] = z; }
  const unsigned short* Ap = A + (size_t)(m0 + r0) * C_ + o0;
  const unsigned short* Bwp = WwT + (size_t)(n0 + r0) * C_ + o0;
  const unsigned short* Bgp = WgT + (size_t)(n0 + r0) * C_ + o0;
  for (int k0 = 0; k0 < C_; k0 += 32){
    short8 a0 = *(const short8*)(Ap + k0);
    short8 a1 = *(const short8*)(Ap + (size_t)64*C_ + k0);
    short8 b0, c0;
    if (r0 < 64){
      b0 = *(const short8*)(Bwp + k0);
      c0 = *(const short8*)(Bgp + k0);
    }
    __syncthreads();
    *(short8*)(As + r0*40 + o0)      = a0;
    *(short8*)(As + (r0+64)*40 + o0) = a1;
    if (r0 < 64){
      *(short8*)(Bw + r0*40 + o0) = b0;
      *(short8*)(Bg + r0*40 + o0) = c0;
    }
    __syncthreads();
    short8 af[4], bfr[2], cfr[2];
    #pragma unroll
    for (int i = 0; i < 4; i++)
      af[i] = *(const short8*)(As + (wr*64 + i*16 + cl)*40 + cq*8);
    #pragma unroll
    for (int j = 0; j < 2; j++){
      bfr[j] = *(const short8*)(Bw + (wc*32 + j*16 + cl)*40 + cq*8);
      cfr[j] = *(const short8*)(Bg + (wc*32 + j*16 + cl)*40 + cq*8);
    }
    #pragma unroll
    for (int i = 0; i < 4; i++)
      #pragma unroll
      for (int j = 0; j < 2; j++){
        acc1[i][j] = __builtin_amdgcn_mfma_f32_16x16x32_bf16(af[i], bfr[j], acc1[i][j], 0, 0, 0);
        acc2[i][j] = __builtin_amdgcn_mfma_f32_16x16x32_bf16(af[i], cfr[j], acc2[i][j], 0, 0, 0);
      }
  }
  #pragma unroll
  for (int j = 0; j < 2; j++){
    int n = n0 + wc*32 + j*16 + cl;
    #pragma unroll
    for (int i = 0; i < 4; i++){
      #pragma unroll
      for (int r = 0; r < 4; r++){
        int m = m0 + wr*64 + i*16 + cq*4 + r;
        float v = (n < F_) ? gelu_exact(acc1[i][j][r]) * acc2[i][j][r] : 0.f;
        fout[(size_t)m*FP_ + n] = __float2bfloat16(v);
      }
    }
  }
}

// ---------------- FFN down + LayerScale residual ----------------
__global__ __launch_bounds__(256) void k_down(const bf16* Abuf, const unsigned short* WT,
                                              const float* xbuf, const void* gamma2,
                                              const int* flags, void* out){
  __shared__ unsigned short As[128*40], Bs[128*40];
  int fg = flags[16], fo = flags[0];
  int m0 = blockIdx.x * 128, n0 = blockIdx.y * 128;
  f32x4 acc[4][4];
  #pragma unroll
  for (int i = 0; i < 4; i++)
    #pragma unroll
    for (int j = 0; j < 4; j++){ f32x4 z = {0.f,0.f,0.f,0.f}; acc[i][j] = z; }
  gemm128_core((const unsigned short*)Abuf, WT, FP_, m0, n0, As, Bs, acc);
  int t = threadIdx.x, lane = t & 63, w = t >> 6, wr = w >> 1, wc = w & 1;
  int cl = lane & 15, cq = lane >> 4;
  #pragma unroll
  for (int j = 0; j < 4; j++){
    int n = n0 + wc*64 + j*16 + cl;
    float gv = ldf(gamma2, n, fg);
    #pragma unroll
    for (int i = 0; i < 4; i++){
      #pragma unroll
      for (int r = 0; r < 4; r++){
        int m = m0 + wr*64 + i*16 + cq*4 + r;
        size_t idx = (size_t)m*C_ + n;
        float val = xbuf[idx] + gv * acc[i][j][r];
        if (fo) ((bf16*)out)[idx] = __float2bfloat16(val);
        else    ((float*)out)[idx] = val;
      }
    }
  }
}

// ---------------- Vsum[b][g][d] = sum_m V ----------------
__global__ __launch_bounds__(256) void k_vsum(const bf16* vb, float* vsum){
  __shared__ float red[8][32];
  int bg = blockIdx.x;
  int t = threadIdx.x;
  int d = t & 31, mg = t >> 5;
  float s = 0.f;
  for (int m = mg*128; m < mg*128 + 128; m++)
    s += b2f(vb[((size_t)bg*N_ + m)*D_ + d]);
  red[mg][d] = s; __syncthreads();
  if (t < 32){
    float a = 0.f;
    #pragma unroll
    for (int i = 0; i < 8; i++) a += red[i][t];
    vsum[(size_t)bg*D_ + t] = a;
  }
}

// ============ Pass A: scores -> P = exp(s) (bf16, no max) + row-sums L ============
// grid (64 ntiles, 8 b, 2 z) ; z = m-half. Each wave: 128 m's (4 chunks of 32).
__global__ __launch_bounds__(256) void k_passA(const bf16* qb, const bf16* kb,
                                               const void* Wt1, const void* bt1, const void* inter,
                                               const int* flags, const int* lengths,
                                               unsigned short* P, float* Lp){
  __shared__ float w1s[64], b1v[8];
  __shared__ unsigned short ps[4][8][640];   // [wave][g][n*40 + m(0..31)]
  __shared__ float swL[4][8][16];
  int fw1 = flags[5], fb1 = flags[6], fint = flags[2];
  int t = threadIdx.x;
  int ntile = blockIdx.x, b = blockIdx.y, z = blockIdx.z;
  int n0 = ntile * 16;
  int len = lengths[b];
  if (t < 64) w1s[t] = ldf(Wt1, t, fw1) * 0.17677669529663687f;  // fold 1/sqrt(32)
  if (t < 8)  b1v[t] = ldf(bt1, t, fb1);
  __syncthreads();
  int lane = t & 63, w = t >> 6;
  int c = lane & 15, q = lane >> 4;
  const unsigned short* qus = (const unsigned short*)qb;
  const unsigned short* kus = (const unsigned short*)kb;
  short8 qfrag[8];
  #pragma unroll
  for (int h = 0; h < 8; h++)
    qfrag[h] = *(const short8*)(qus + (((size_t)b*8 + h)*N_ + n0 + c)*D_ + q*8);
  float Lacc[8][4];
  #pragma unroll
  for (int g = 0; g < 8; g++)
    #pragma unroll
    for (int r = 0; r < 4; r++) Lacc[g][r] = 0.f;

  for (int ci = 0; ci < 4; ci++){
    int m0c = z*512 + w*128 + ci*32;
    #pragma unroll
    for (int mt = 0; mt < 2; mt++){
      int m0t = m0c + mt*16;
      f32x4 sfr[8];
      #pragma unroll
      for (int h = 0; h < 8; h++){
        short8 kf = *(const short8*)(kus + (((size_t)b*8 + h)*N_ + m0t + c)*D_ + q*8);
        f32x4 zz = {0.f,0.f,0.f,0.f};
        sfr[h] = __builtin_amdgcn_mfma_f32_16x16x32_bf16(qfrag[h], kf, zz, 0, 0, 0);
      }
      int m_g = m0t + c;
      bool mok = (m_g < len);
      #pragma unroll
      for (int r = 0; r < 4; r++){
        int n_l = q*4 + r, n_gg = n0 + n_l;
        size_t i8 = ((size_t)b*N_ + n_gg)*N_ + m_g;
        float ifl[8];
        if (fint){
          uint4 iv = *(const uint4*)((const unsigned short*)inter + i8*8);
          ifl[0]=us2f(iv.x&0xffffu); ifl[1]=us2f(iv.x>>16);
          ifl[2]=us2f(iv.y&0xffffu); ifl[3]=us2f(iv.y>>16);
          ifl[4]=us2f(iv.z&0xffffu); ifl[5]=us2f(iv.z>>16);
          ifl[6]=us2f(iv.w&0xffffu); ifl[7]=us2f(iv.w>>16);
        } else {
          const float* fp = (const float*)inter + i8*8;
          #pragma unroll
          for (int g = 0; g < 8; g++) ifl[g] = fp[g];
        }
        bool ok = (n_gg >= len) || mok;
        #pragma unroll
        for (int g = 0; g < 8; g++){
          float v = b1v[g] + ifl[g];
          #pragma unroll
          for (int h = 0; h < 8; h++) v += sfr[h][r] * w1s[h*8 + g];
          float e = ok ? __expf(v) : 0.f;
          Lacc[g][r] += e;
          ps[w][g][n_l*40 + mt*16 + c] = f2bu(e);
        }
      }
    }
    // store this 32-m chunk: 128 rows (8g x 16n) of 64B, 16 rows/iter
    #pragma unroll
    for (int it = 0; it < 8; it++){
      int row = it*16 + (lane >> 2);
      int g = row >> 4, n = row & 15, chunk = lane & 3;
      short8 pv = *(const short8*)&ps[w][g][n*40 + chunk*8];
      *(short8*)(P + (((size_t)b*8 + g)*N_ + n0 + n)*N_ + m0c + chunk*8) = pv;
    }
  }
  // reduce L over the 16 m-columns within each quad (lanes sharing q)
  #pragma unroll
  for (int g = 0; g < 8; g++)
    #pragma unroll
    for (int r = 0; r < 4; r++){
      float v = Lacc[g][r];
      v += __shfl_xor(v, 1); v += __shfl_xor(v, 2);
      v += __shfl_xor(v, 4); v += __shfl_xor(v, 8);
      Lacc[g][r] = v;
    }
  if (c == 0){
    #pragma unroll
    for (int g = 0; g < 8; g++)
      #pragma unroll
      for (int r = 0; r < 4; r++) swL[w][g][q*4 + r] = Lacc[g][r];
  }
  __syncthreads();
  if (t < 128){
    int g = t >> 4, nl = t & 15;
    float Lf = swL[0][g][nl] + swL[1][g][nl] + swL[2][g][nl] + swL[3][g][nl];
    Lp[(((size_t)b*8 + g)*N_ + n0 + nl)*2 + z] = Lf;
  }
}

// ============ Pass B: P -> normalize -> th2 mix (in-register, A-frag layout) -> PV ============
// grid (64 ntiles, 8 b, 2 zh) ; zh = gg-half (4 output heads each). No K/QK^T/exp here.
__global__ __launch_bounds__(256) void k_passB(const unsigned short* P, const unsigned short* vt,
                                               const void* Wt2, const void* bt2,
                                               const int* flags, const float* Lp,
                                               const float* vsum, bf16* aobuf){
  __shared__ float w2s[64], b2v[8];
  __shared__ float rLs[8][16];
  __shared__ float vsumS[4][32];
  __shared__ float osum[4][528];              // [wave][n*33 + d]
  int fw2 = flags[7], fb2 = flags[8];
  int t = threadIdx.x;
  int ntile = blockIdx.x, b = blockIdx.y, zh = blockIdx.z;
  int n0 = ntile * 16;
  if (t < 64) w2s[t] = ldf(Wt2, t, fw2);
  if (t < 8)  b2v[t] = ldf(bt2, t, fb2);
  if (t < 128){
    int g = t >> 4, nl = t & 15;
    const float* lp = Lp + (((size_t)b*8 + g)*N_ + n0 + nl)*2;
    rLs[g][nl] = 1.0f / (lp[0] + lp[1]);
  }
  if (t >= 128 && t < 256){
    int e = t - 128;
    int g2 = e >> 5, d = e & 31;
    vsumS[g2][d] = vsum[((size_t)b*8 + zh*4 + g2)*D_ + d];
  }
  __syncthreads();
  int lane = t & 63, w = t >> 6;
  int c = lane & 15, q = lane >> 4;
  float rL[8];
  #pragma unroll
  for (int g = 0; g < 8; g++) rL[g] = rLs[g][c];
  float w2r[8][4];
  #pragma unroll
  for (int g = 0; g < 8; g++)
    #pragma unroll
    for (int j = 0; j < 4; j++) w2r[g][j] = w2s[g*8 + zh*4 + j];
  f32x4 acc[4][2];
  #pragma unroll
  for (int gg = 0; gg < 4; gg++){ f32x4 z = {0.f,0.f,0.f,0.f}; acc[gg][0] = z; acc[gg][1] = z; }

  for (int ci = 0; ci < 8; ci++){
    int m0c = w*256 + ci*32;
    short8 pf[8];
    #pragma unroll
    for (int g = 0; g < 8; g++)
      pf[g] = *(const short8*)(P + (((size_t)b*8 + g)*N_ + n0 + c)*N_ + m0c + q*8);
    float a2[4][8];
    #pragma unroll
    for (int gg = 0; gg < 4; gg++)
      #pragma unroll
      for (int j = 0; j < 8; j++) a2[gg][j] = 0.f;
    #pragma unroll
    for (int j = 0; j < 8; j++){
      #pragma unroll
      for (int g = 0; g < 8; g++){
        float png = us2f((unsigned int)(unsigned short)pf[g][j]) * rL[g];
        a2[0][j] += png * w2r[g][0];
        a2[1][j] += png * w2r[g][1];
        a2[2][j] += png * w2r[g][2];
        a2[3][j] += png * w2r[g][3];
      }
    }
    #pragma unroll
    for (int gg = 0; gg < 4; gg++){
      short8 af;
      #pragma unroll
      for (int j = 0; j < 8; j++) af[j] = (short)f2bu(a2[gg][j]);
      int ggg = zh*4 + gg;
      short8 bf0 = *(const short8*)(vt + (((size_t)b*8 + ggg)*D_ + c)*N_ + m0c + q*8);
      short8 bf1 = *(const short8*)(vt + (((size_t)b*8 + ggg)*D_ + 16 + c)*N_ + m0c + q*8);
      acc[gg][0] = __builtin_amdgcn_mfma_f32_16x16x32_bf16(af, bf0, acc[gg][0], 0, 0, 0);
      acc[gg][1] = __builtin_amdgcn_mfma_f32_16x16x32_bf16(af, bf1, acc[gg][1], 0, 0, 0);
    }
  }
  // epilogue: reduce 4 waves' partial O, add bt2 * Vsum, store bf16
  for (int gg = 0; gg < 4; gg++){
    #pragma unroll
    for (int dt = 0; dt < 2; dt++)
      #pragma unroll
      for (int r = 0; r < 4; r++)
        osum[w][(q*4 + r)*33 + dt*16 + c] = acc[gg][dt][r];
    __syncthreads();
    int ggg = zh*4 + gg;
    #pragma unroll
    for (int e = t; e < 512; e += 256){
      int nl = e >> 5, d = e & 31;
      float val = osum[0][nl*33 + d] + osum[1][nl*33 + d]
                + osum[2][nl*33 + d] + osum[3][nl*33 + d]
                + b2v[ggg] * vsumS[gg][d];
      aobuf[((size_t)b*N_ + n0 + nl)*C_ + ggg*D_ + d] = __float2bfloat16(val);
    }
    __syncthreads();
  }
}

// ---------------- launcher ----------------
extern "C" void kernel_launch(void* const* d_in, const int* in_sizes, int n_in,
                              void* d_out, int out_size, void* d_ws, size_t ws_size,
                              hipStream_t stream) {
  Ptrs ptrs;
  for (int i = 0; i < 22; i++) ptrs.p[i] = d_in[i];
  const unsigned char* mask = (const unsigned char*)d_in[1];

  char* ws = (char*)d_ws;
  size_t o = 0;
  size_t o_flags = o; o += 256;
  size_t o_len   = o; o += 256;
  size_t o_L     = o; o += (size_t)B_*H_*N_*2*4;              // 512 KB (L partials)
  size_t o_vsum  = o; o += (size_t)B_*H_*D_*4;                // 8 KB
  size_t o_h     = o; o += (size_t)B_*N_*C_*2;                // 4 MB bf16
  size_t o_q     = o; o += (size_t)B_*N_*C_*2;
  size_t o_k     = o; o += (size_t)B_*N_*C_*2;
  size_t o_v     = o; o += (size_t)B_*N_*C_*2;
  size_t o_vt    = o; o += (size_t)B_*N_*C_*2;                // 4 MB Vt
  size_t o_ao    = o; o += (size_t)B_*N_*C_*2;                // 4 MB bf16
  size_t o_x     = o; o += (size_t)B_*N_*C_*4;                // 8 MB f32
  size_t o_f     = o; o += (size_t)B_*N_*FP_*2;               // 11.5 MB bf16 (stride 704)
  size_t o_wq    = o; o += (size_t)768*256*2;
  size_t o_wo    = o; o += (size_t)256*256*2;
  size_t o_ww    = o; o += (size_t)FP_*256*2;
  size_t o_wg    = o; o += (size_t)FP_*256*2;
  size_t o_wd    = o; o += (size_t)256*FP_*2;
  size_t o_P     = o; o += (size_t)B_*H_*N_*N_*2;             // 128 MB bf16

  int*    flags   = (int*)(ws + o_flags);
  int*    lengths = (int*)(ws + o_len);
  float*  Lp      = (float*)(ws + o_L);
  float*  vsum    = (float*)(ws + o_vsum);
  bf16*   hbuf    = (bf16*)(ws + o_h);
  bf16*   qbuf    = (bf16*)(ws + o_q);
  bf16*   kbuf    = (bf16*)(ws + o_k);
  bf16*   vbuf    = (bf16*)(ws + o_v);
  unsigned short* vtbuf = (unsigned short*)(ws + o_vt);
  bf16*   aobuf   = (bf16*)(ws + o_ao);
  float*  xbuf    = (float*)(ws + o_x);
  bf16*   fbuf    = (bf16*)(ws + o_f);
  unsigned short* wqkvT  = (unsigned short*)(ws + o_wq);
  unsigned short* woutT  = (unsigned short*)(ws + o_wo);
  unsigned short* wwideT = (unsigned short*)(ws + o_ww);
  unsigned short* wgateT = (unsigned short*)(ws + o_wg);
  unsigned short* wdownT = (unsigned short*)(ws + o_wd);
  unsigned short* Pbuf   = (unsigned short*)(ws + o_P);

  k_sniffp<<<22, 64, 0, stream>>>(ptrs, flags);
  k_prepw<<<dim3(192, 5), 256, 0, stream>>>(ptrs, flags, wqkvT, woutT, wwideT, wgateT, wdownT);
  k_lengths<<<8, 256, 0, stream>>>(mask, lengths);
  k_ln<<<B_*N_, 256, 0, stream>>>(d_in[0], flags, 0, d_in[11], 11, d_in[12], 12, hbuf, 1, C_, C_);
  k_qkv<<<dim3(64, 6), 256, 0, stream>>>(hbuf, wqkvT, d_in[4], flags, qbuf, kbuf, vbuf);
  k_vt<<<dim3(32, 64), 256, 0, stream>>>(vbuf, vtbuf);
  k_vsum<<<64, 256, 0, stream>>>(vbuf, vsum);
  k_passA<<<dim3(64, 8, 2), 256, 0, stream>>>(qbuf, kbuf, d_in[5], d_in[6], d_in[2],
                                              flags, lengths, Pbuf, Lp);
  k_passB<<<dim3(64, 8, 2), 256, 0, stream>>>(Pbuf, vtbuf, d_in[7], d_in[8],
                                              flags, Lp, vsum, aobuf);
  k_outproj<<<dim3(64, 2), 256, 0, stream>>>(aobuf, woutT, d_in[10], d_in[0], d_in[15], flags, xbuf);
  k_ln<<<B_*N_, 256, 0, stream>>>(xbuf, flags, -1, d_in[13], 13, d_in[14], 14, hbuf, 1, C_, C_);
  k_ffn1<<<dim3(64, 11), 256, 0, stream>>>(hbuf, wwideT, wgateT, fbuf);
  k_ln<<<B_*N_, 256, 0, stream>>>(fbuf, flags, -2, d_in[20], 20, d_in[21], 21, fbuf, 1, F_, FP_);
  k_down<<<dim3(64, 2), 256, 0, stream>>>(fbuf, wdownT, xbuf, d_in[16], flags, d_out);
}